// Round 3
// baseline (57.071 us; speedup 1.0000x reference)
//
#include <hip/hip_runtime.h>
#include <math.h>

#define BB 4
#define CC 19
#define HH 512
#define WW 1024
#define NPIX (HH * WW)          // 524288 = 2^19
#define NB 160                  // histogram bins over max_prob in [0,1]
#define NBP 165                 // padded LDS row stride (165%32=5, odd -> ~conflict-free)
#define CONF_BIN 144            // 0.9 * 160 exactly -> bin>=144 <=> p>=0.9
#define FRACTION_F 0.66f
#define ROW (CC * NB)           // 3040 bins per image-block histogram
#define NROW (BB * CC)          // 76
#define NCOL (NROW * NB)        // 12160 (row, bin) columns

#define NBLK1 512
#define BLKS_PER_IMG (NBLK1 / BB)         // 128
#define PIX_PER_BLK (NPIX / BLKS_PER_IMG) // 4096
#define ITERS (PIX_PER_BLK / (256 * 4))   // 4

// ws layout:
//   int   cntPart[NBLK1][ROW]   (6.23 MB)
//   float snlPart[NBLK1][ROW]   (6.23 MB)
//   int   redCnt[NCOL]          (48.6 KB)
//   float redSnl[NCOL]          (48.6 KB)

__global__ __launch_bounds__(256, 2) void st_pass1(const float* __restrict__ pred,
                                                   int* __restrict__ cntPart,
                                                   float* __restrict__ snlPart) {
    __shared__ int   hcnt[ROW];
    __shared__ float hsnl[ROW];
    int tid = threadIdx.x;
    for (int i = tid; i < ROW; i += 256) { hcnt[i] = 0; hsnl[i] = 0.f; }
    __syncthreads();

    int blk = blockIdx.x;
    int b   = blk >> 7;                  // / BLKS_PER_IMG
    int seg = blk & (BLKS_PER_IMG - 1);
    const float* base = pred + (size_t)b * CC * NPIX + (size_t)seg * PIX_PER_BLK;

    for (int it = 0; it < ITERS; ++it) {
        const float* bp = base + it * 1024 + tid * 4;
        // issue all 19 channel loads first -> 19 outstanding per thread
        float4 v[CC];
        #pragma unroll
        for (int c = 0; c < CC; ++c)
            v[c] = *(const float4*)(bp + (size_t)c * NPIX);

        #pragma unroll
        for (int j = 0; j < 4; ++j) {
            float m = ((const float*)&v[0])[j];
            float s = 1.f;
            int   arg = 0;
            #pragma unroll
            for (int c = 1; c < CC; ++c) {
                float x  = ((const float*)&v[c])[j];
                float nm = fmaxf(m, x);
                s = s * __expf(m - nm) + __expf(x - nm);
                arg = (x > m) ? c : arg;     // strict > keeps first max (jnp.argmax)
                m = nm;
            }
            float prob = 1.f / s;            // max softmax prob
            float nll  = __logf(s);          // -log(max_prob)
            int bin = (int)(prob * (float)NB);
            bin = min(bin, NB - 1);
            int idx = arg * NB + bin;
            atomicAdd(&hcnt[idx], 1);        // LDS atomics: CU-local, cheap
            atomicAdd(&hsnl[idx], nll);
        }
    }
    __syncthreads();

    // flush private slice with plain coalesced stores (no global atomics)
    int*   cp = cntPart + (size_t)blk * ROW;
    float* sp = snlPart + (size_t)blk * ROW;
    for (int i = tid; i < ROW; i += 256) { cp[i] = hcnt[i]; sp[i] = hsnl[i]; }
}

// Reduce 128 partials per (row,bin) column. Thread-per-column, coalesced,
// 4 accumulator streams + unroll -> ~16 loads in flight per thread.
__global__ __launch_bounds__(128) void st_pass2a(const int* __restrict__ cntPart,
                                                 const float* __restrict__ snlPart,
                                                 int* __restrict__ redCnt,
                                                 float* __restrict__ redSnl) {
    int col = blockIdx.x * 128 + threadIdx.x;   // 0..NCOL-1
    int r   = col / NB;                         // row = b*CC + c
    int bin = col - r * NB;
    int b = r / CC, c = r - b * CC;
    size_t base = (size_t)(b * BLKS_PER_IMG) * ROW + (size_t)(c * NB + bin);

    int   cs0 = 0, cs1 = 0;
    float ss0 = 0.f, ss1 = 0.f;
    #pragma unroll 8
    for (int p = 0; p < BLKS_PER_IMG; p += 2) {
        cs0 += cntPart[base + (size_t)p * ROW];
        cs1 += cntPart[base + (size_t)(p + 1) * ROW];
        ss0 += snlPart[base + (size_t)p * ROW];
        ss1 += snlPart[base + (size_t)(p + 1) * ROW];
    }
    redCnt[col] = cs0 + cs1;
    redSnl[col] = ss0 + ss1;
}

// Stage reduced histograms to LDS (padded stride), 76 threads scan for the
// rank cutoff, block-reduce to the final loss. Replaces old pass2+pass3.
__global__ __launch_bounds__(1024) void st_pass2b(const int* __restrict__ redCnt,
                                                  const float* __restrict__ redSnl,
                                                  float* __restrict__ out) {
    __shared__ int   scnt[NROW * NBP];
    __shared__ float ssnl[NROW * NBP];
    __shared__ float sred[128];
    int tid = threadIdx.x;

    for (int e = tid; e < NCOL; e += 1024) {
        int r = e / NB;
        int i = e - r * NB;
        scnt[r * NBP + i] = redCnt[e];      // global read coalesced; LDS write consecutive
        ssnl[r * NBP + i] = redSnl[e];
    }
    __syncthreads();

    float sel = 0.f;
    if (tid < NROW) {
        const int*   h  = scnt + tid * NBP;
        const float* sn = ssnl + tid * NBP;
        int count = 0;
        #pragma unroll 8
        for (int i = 0; i < NB; ++i) count += h[i];
        float conf = 0.f;                    // sum of nll where p >= 0.9
        #pragma unroll 8
        for (int i = CONF_BIN; i < NB; ++i) conf += sn[i];
        int k = (int)floorf((float)count * FRACTION_F);  // match jnp f32 math
        if (k == 0) {
            sel = conf;
        } else {
            int cum = 0;                     // count in bins strictly above boundary
            float csum = 0.f;
            int bin = NB - 1;
            int hh = 0;
            for (; bin >= 0; --bin) {
                hh = h[bin];
                if (cum + hh >= k) break;    // rank k-1 lies in this bin
                cum += hh;
                csum += sn[bin];
            }
            if (bin < 0) {
                sel = csum;                  // safety (k < count always)
            } else if (bin >= CONF_BIN) {
                sel = conf;                  // cutoff >= 0.9 -> union == {p>0.9}
            } else {
                float avg = sn[bin] / (float)max(hh, 1);
                sel = csum + (float)(k - cum) * avg;
            }
        }
    }

    if (tid < 128) sred[tid] = 0.f;
    __syncthreads();
    if (tid < NROW) sred[tid] = sel;
    __syncthreads();
    for (int off = 64; off > 0; off >>= 1) {
        if (tid < off) sred[tid] += sred[tid + off];
        __syncthreads();
    }
    if (tid == 0) out[0] = sred[0] * (1.0f / (float)(BB * (size_t)NPIX));
}

extern "C" void kernel_launch(void* const* d_in, const int* in_sizes, int n_in,
                              void* d_out, int out_size, void* d_ws, size_t ws_size,
                              hipStream_t stream) {
    const float* pred = (const float*)d_in[0];
    float* out = (float*)d_out;

    char* ws = (char*)d_ws;
    int*   cntPart = (int*)ws;
    float* snlPart = (float*)(ws + (size_t)NBLK1 * ROW * sizeof(int));
    int*   redCnt  = (int*)(ws + (size_t)NBLK1 * ROW * (sizeof(int) + sizeof(float)));
    float* redSnl  = (float*)(ws + (size_t)NBLK1 * ROW * (sizeof(int) + sizeof(float)) + (size_t)NCOL * sizeof(int));

    st_pass1<<<NBLK1, 256, 0, stream>>>(pred, cntPart, snlPart);
    st_pass2a<<<NCOL / 128, 128, 0, stream>>>(cntPart, snlPart, redCnt, redSnl);
    st_pass2b<<<1, 1024, 0, stream>>>(redCnt, redSnl, out);
}